// Round 3
// baseline (298.147 us; speedup 1.0000x reference)
//
#include <hip/hip_runtime.h>

// ---------------------------------------------------------------------------
// StandardMultiHeadAttention: B=2, S=2048, D=1024, H=16, Dh=64, causal.
// Pipeline: fp32->f16 convert -> QKV GEMM (MFMA) -> flash attention (MFMA)
//           -> output GEMM (MFMA, fp32 out).
// Workspace layout (48 MB total):
//   [0,8M)    xb   : x as f16 [4096,1024]
//   [8M,16M)  wb   : Wq,Wk,Wv,Wo as f16, 2MB each (row=out, K-major)
//   [16M,40M) qkv  : Q [B,H,S,64] (pre-scaled by 0.125), K [B,H,S,64],
//                    Vt [B,H,64,S], f16, 8MB each
//   [40M,48M) ob   : attention output [B,S,1024] f16
//
// R1: attn 64-row q blocks, reversed dispatch, Ps stride 68. 117->84 us.
// R2: attn was LDS-pipe-bound (~360 LDS cyc/wave-tile vs 77 MFMA cyc).
//     K/V fragments now loaded DIRECTLY global->register (fragment layout
//     is a plain 16B/lane load from K[B,H,S,64] / Vt[B,H,64,S]; L1/L2
//     serve the reuse). No more Ks/Vs staging, no __syncthreads at all —
//     only P's C-layout->A-layout transform still round-trips LDS.
// ---------------------------------------------------------------------------

typedef _Float16 f16x8 __attribute__((ext_vector_type(8)));
typedef _Float16 f16x4 __attribute__((ext_vector_type(4)));
typedef float f32x4 __attribute__((ext_vector_type(4)));

#define S_  2048
#define DM  1024
#define NH  16
#define DH  64

__device__ __forceinline__ void gload_lds16(const void* g, void* s) {
  __builtin_amdgcn_global_load_lds(
      (const __attribute__((address_space(1))) void*)g,
      (__attribute__((address_space(3))) void*)s, 16, 0, 0);
}

// ----------------------------- convert kernels -----------------------------

__global__ void cvt_x_kernel(const float* __restrict__ src,
                             _Float16* __restrict__ dst) {
  const int i = blockIdx.x * 256 + threadIdx.x;   // exact: 4096*256 float4s
  const float4 v = ((const float4*)src)[i];
  f16x4 h;
  h[0] = (_Float16)v.x; h[1] = (_Float16)v.y;
  h[2] = (_Float16)v.z; h[3] = (_Float16)v.w;
  ((f16x4*)dst)[i] = h;
}

__global__ void cvt_w_kernel(const float* __restrict__ w0,
                             const float* __restrict__ w1,
                             const float* __restrict__ w2,
                             const float* __restrict__ w3,
                             _Float16* __restrict__ dst) {
  const int y = blockIdx.y;
  const float* src = (y == 0) ? w0 : (y == 1) ? w1 : (y == 2) ? w2 : w3;
  const int i = blockIdx.x * 256 + threadIdx.x;   // exact: 1024*256 float4s
  const float4 v = ((const float4*)src)[i];
  f16x4 h;
  h[0] = (_Float16)v.x; h[1] = (_Float16)v.y;
  h[2] = (_Float16)v.z; h[3] = (_Float16)v.w;
  ((f16x4*)(dst + (size_t)y * (DM * DM)))[i] = h;
}

// ------------------------------- GEMM core ---------------------------------
// C[128,128] += A[128x1024] * W[128x1024]^T  (both K-major, f16).
// m97 structure: 128x128 tile, BK=32, global_load_lds width 16, 2 barriers.

__device__ __forceinline__ void gemm_core_k1024(
    const _Float16* __restrict__ A, const _Float16* __restrict__ W,
    _Float16* As, _Float16* Ws, f32x4 acc[4][4], int m0, int n0)
{
  const int t = threadIdx.x;
  const int w = t >> 6, l = t & 63;
  const int quad = l >> 4, ln = l & 15;
  const int wm = (w >> 1) << 6, wn = (w & 1) << 6;
  const int srow = l >> 2, scol = (l & 3) << 3;

  for (int k0 = 0; k0 < DM; k0 += 32) {
#pragma unroll
    for (int i = 0; i < 2; ++i) {
      const int ra = w * 32 + i * 16;   // 16 rows per wave-issue
      gload_lds16(&A[(size_t)(m0 + ra + srow) * DM + k0 + scol], &As[ra * 32]);
      gload_lds16(&W[(size_t)(n0 + ra + srow) * DM + k0 + scol], &Ws[ra * 32]);
    }
    __syncthreads();   // drains vmcnt -> staged tiles visible

    f16x8 af[4], bf[4];
#pragma unroll
    for (int mi = 0; mi < 4; ++mi)
      af[mi] = *(const f16x8*)&As[(wm + mi * 16 + ln) * 32 + quad * 8];
#pragma unroll
    for (int ni = 0; ni < 4; ++ni)
      bf[ni] = *(const f16x8*)&Ws[(wn + ni * 16 + ln) * 32 + quad * 8];
#pragma unroll
    for (int mi = 0; mi < 4; ++mi)
#pragma unroll
      for (int ni = 0; ni < 4; ++ni)
        acc[mi][ni] = __builtin_amdgcn_mfma_f32_16x16x32_f16(
            af[mi], bf[ni], acc[mi][ni], 0, 0, 0);
    __syncthreads();   // before next stage overwrites LDS
  }
}

// z=0: Q (bias, *0.125, [B,H,S,64]); z=1: K (bias, [B,H,S,64]);
// z=2: V (bias, transposed [B,H,64,S])
__global__ __launch_bounds__(256, 2) void gemm_qkv_kernel(
    const _Float16* __restrict__ xb, const _Float16* __restrict__ wb,
    const float* __restrict__ bq, const float* __restrict__ bk,
    const float* __restrict__ bv, _Float16* __restrict__ qkv)
{
  __shared__ _Float16 As[128 * 32];
  __shared__ _Float16 Ws[128 * 32];
  const int z = blockIdx.z;
  const _Float16* W = wb + (size_t)z * (DM * DM);
  const float* bias = (z == 0) ? bq : ((z == 1) ? bk : bv);
  _Float16* out = qkv + (size_t)z * ((size_t)4096 * DM);

  const f32x4 z4 = {0.f, 0.f, 0.f, 0.f};
  f32x4 acc[4][4];
#pragma unroll
  for (int mi = 0; mi < 4; ++mi)
#pragma unroll
    for (int ni = 0; ni < 4; ++ni) acc[mi][ni] = z4;

  const int m0 = blockIdx.y * 128, n0 = blockIdx.x * 128;
  gemm_core_k1024(xb, W, As, Ws, acc, m0, n0);

  const int t = threadIdx.x, w = t >> 6, l = t & 63;
  const int quad = l >> 4, ln = l & 15;
  const int wm = (w >> 1) << 6, wn = (w & 1) << 6;
  const float scale = (z == 0) ? 0.125f : 1.0f;   // 1/sqrt(Dh) folded into Q

#pragma unroll
  for (int ni = 0; ni < 4; ++ni) {
    const int c = n0 + wn + ni * 16 + ln;
    const float bias_c = bias[c];
    const int h = c >> 6, d = c & 63;
#pragma unroll
    for (int mi = 0; mi < 4; ++mi) {
      const int mb = m0 + wm + mi * 16 + quad * 4;
#pragma unroll
      for (int r = 0; r < 4; ++r) {
        const int mg = mb + r;
        const int b = mg >> 11, s = mg & 2047;
        const float v = (acc[mi][ni][r] + bias_c) * scale;
        if (z == 2)
          out[((size_t)(b * NH + h) * DH + d) * S_ + s] = (_Float16)v;
        else
          out[((size_t)(b * NH + h) * S_ + s) * DH + d] = (_Float16)v;
      }
    }
  }
}

__global__ __launch_bounds__(256, 2) void gemm_out_kernel(
    const _Float16* __restrict__ ob, const _Float16* __restrict__ wo,
    const float* __restrict__ bo, float* __restrict__ out)
{
  __shared__ _Float16 As[128 * 32];
  __shared__ _Float16 Ws[128 * 32];
  const f32x4 z4 = {0.f, 0.f, 0.f, 0.f};
  f32x4 acc[4][4];
#pragma unroll
  for (int mi = 0; mi < 4; ++mi)
#pragma unroll
    for (int ni = 0; ni < 4; ++ni) acc[mi][ni] = z4;

  const int m0 = blockIdx.y * 128, n0 = blockIdx.x * 128;
  gemm_core_k1024(ob, wo, As, Ws, acc, m0, n0);

  const int t = threadIdx.x, w = t >> 6, l = t & 63;
  const int quad = l >> 4, ln = l & 15;
  const int wm = (w >> 1) << 6, wn = (w & 1) << 6;

#pragma unroll
  for (int ni = 0; ni < 4; ++ni) {
    const int c = n0 + wn + ni * 16 + ln;
    const float bias_c = bo[c];
#pragma unroll
    for (int mi = 0; mi < 4; ++mi) {
      const int mb = m0 + wm + mi * 16 + quad * 4;
#pragma unroll
      for (int r = 0; r < 4; ++r)
        out[(size_t)(mb + r) * DM + c] = acc[mi][ni][r] + bias_c;
    }
  }
}

// ---------------------------- flash attention ------------------------------
// R2: grid (bh=32, qi=32 reversed). 64 q rows/block, 4 waves, each wave owns
// one 16-row MFMA tile. KV tiles of 64. K/V fragments loaded directly
// global->register (B-operand layout == contiguous 16B in K / Vt). No LDS
// staging, no barriers. Only P goes through LDS (stride 68, conflict-free).

__global__ __launch_bounds__(256, 4) void attn_kernel(
    const _Float16* __restrict__ Qb, const _Float16* __restrict__ Kb,
    const _Float16* __restrict__ Vtb, _Float16* __restrict__ Ob)
{
  __shared__ _Float16 Ps[64 * 68];   // [q][kv], wave-private 16-row slices

  const int qi = 31 - blockIdx.y;    // longest blocks (most KV tiles) first
  const int qb0 = qi << 6;
  const int bh = blockIdx.x;
  const int bidx = bh >> 4, h = bh & 15;
  const _Float16* Qh = Qb + (size_t)bh * (S_ * DH);
  const _Float16* Kh = Kb + (size_t)bh * (S_ * DH);
  const _Float16* Vh = Vtb + (size_t)bh * (DH * S_);

  const int t = threadIdx.x, w = t >> 6, l = t & 63;
  const int quad = l >> 4, ln = l & 15;

  // Q fragments (A-operand layout): row qb0+w*16+ln, k=ks*32+quad*8
  f16x8 qf[2];
#pragma unroll
  for (int ks = 0; ks < 2; ++ks)
    qf[ks] = *(const f16x8*)
        &Qh[(size_t)(qb0 + w * 16 + ln) * DH + ks * 32 + quad * 8];

  // per-lane fragment base pointers
  // kf[ni](ks) = Kh[(kb + ni*16 + ln)*64 + ks*32 + quad*8]
  const _Float16* kp = Kh + (size_t)ln * DH + quad * 8;
  // vf[di](ks) = Vh[(di*16 + ln)*2048 + kb + ks*32 + quad*8]
  const _Float16* vp = Vh + (size_t)ln * S_ + quad * 8;

  const f32x4 z4 = {0.f, 0.f, 0.f, 0.f};
  f32x4 oacc[4];
  float m_i[4], l_i[4];
#pragma unroll
  for (int di = 0; di < 4; ++di) oacc[di] = z4;
#pragma unroll
  for (int r = 0; r < 4; ++r) { m_i[r] = -__builtin_inff(); l_i[r] = 0.f; }

  for (int kb = 0; kb <= qb0; kb += 64) {
    // S = Q K^T  (pre-scaled by 0.125 via Q); K frags straight from global
    f32x4 sacc[4];
#pragma unroll
    for (int ni = 0; ni < 4; ++ni) sacc[ni] = z4;

#pragma unroll
    for (int ks = 0; ks < 2; ++ks) {
      f16x8 kf[4];
#pragma unroll
      for (int ni = 0; ni < 4; ++ni)
        kf[ni] = *(const f16x8*)&kp[(size_t)(kb + ni * 16) * DH + ks * 32];
#pragma unroll
      for (int ni = 0; ni < 4; ++ni)
        sacc[ni] = __builtin_amdgcn_mfma_f32_16x16x32_f16(
            qf[ks], kf[ni], sacc[ni], 0, 0, 0);
    }

    // causal mask: only the diagonal tile
    if (kb == qb0) {
      const int q = qb0 + w * 16 + quad * 4;
#pragma unroll
      for (int ni = 0; ni < 4; ++ni) {
        const int kv = kb + ni * 16 + ln;
#pragma unroll
        for (int r = 0; r < 4; ++r)
          if (kv > q + r) sacc[ni][r] = -__builtin_inff();
      }
    }

    // online softmax per row (row = quad*4+r within this wave's 16-row tile)
    {
      const int prow = (w * 16 + quad * 4) * 68;
#pragma unroll
      for (int r = 0; r < 4; ++r) {
        float v = fmaxf(fmaxf(sacc[0][r], sacc[1][r]),
                        fmaxf(sacc[2][r], sacc[3][r]));
#pragma unroll
        for (int off = 1; off < 16; off <<= 1) v = fmaxf(v, __shfl_xor(v, off));
        const float mnew = fmaxf(m_i[r], v);
        const float alpha = __expf(m_i[r] - mnew);  // -inf -> 0 first time
        m_i[r] = mnew;
        float rs = 0.f;
#pragma unroll
        for (int ni = 0; ni < 4; ++ni) {
          const float p_ = __expf(sacc[ni][r] - mnew);
          sacc[ni][r] = p_;
          rs += p_;
        }
#pragma unroll
        for (int off = 1; off < 16; off <<= 1) rs += __shfl_xor(rs, off);
        l_i[r] = l_i[r] * alpha + rs;
#pragma unroll
        for (int di = 0; di < 4; ++di) oacc[di][r] *= alpha;
        // P -> LDS (C/D layout scatter; wave-private rows, no barrier needed)
#pragma unroll
        for (int ni = 0; ni < 4; ++ni)
          Ps[prow + r * 68 + ni * 16 + ln] = (_Float16)sacc[ni][r];
      }
    }

    // O += P * V ; V frags straight from global (Vt rows are kv-contiguous)
#pragma unroll
    for (int ks = 0; ks < 2; ++ks) {
      f16x8 pf, vf[4];
      pf = *(const f16x8*)&Ps[(w * 16 + ln) * 68 + ks * 32 + quad * 8];
#pragma unroll
      for (int di = 0; di < 4; ++di)
        vf[di] = *(const f16x8*)&vp[(size_t)(di * 16) * S_ + kb + ks * 32];
#pragma unroll
      for (int di = 0; di < 4; ++di)
        oacc[di] = __builtin_amdgcn_mfma_f32_16x16x32_f16(
            pf, vf[di], oacc[di], 0, 0, 0);
    }
    // no barrier: Ps rows are wave-private, K/V never touch LDS
  }

  // epilogue: O /= l, write [B,S,H*64] f16
#pragma unroll
  for (int r = 0; r < 4; ++r) {
    const float inv = 1.0f / l_i[r];
    const int q = qb0 + w * 16 + quad * 4 + r;
    _Float16* orow = Ob + (size_t)(bidx * S_ + q) * DM + h * DH;
#pragma unroll
    for (int di = 0; di < 4; ++di)
      orow[di * 16 + ln] = (_Float16)(oacc[di][r] * inv);
  }
}

// ------------------------------- launcher ----------------------------------

extern "C" void kernel_launch(void* const* d_in, const int* in_sizes, int n_in,
                              void* d_out, int out_size, void* d_ws, size_t ws_size,
                              hipStream_t stream) {
  (void)in_sizes; (void)n_in; (void)out_size; (void)ws_size;
  const float* x  = (const float*)d_in[0];
  const float* Wq = (const float*)d_in[1];
  const float* bq = (const float*)d_in[2];
  const float* Wk = (const float*)d_in[3];
  const float* bk = (const float*)d_in[4];
  const float* Wv = (const float*)d_in[5];
  const float* bv = (const float*)d_in[6];
  const float* Wo = (const float*)d_in[7];
  const float* bo = (const float*)d_in[8];

  char* ws = (char*)d_ws;
  _Float16* xb  = (_Float16*)(ws);                      // 8 MB
  _Float16* wb  = (_Float16*)(ws + (8u << 20));         // 4 x 2 MB
  _Float16* qkv = (_Float16*)(ws + (16u << 20));        // Q,K,Vt 8 MB each
  _Float16* ob  = (_Float16*)(ws + (40u << 20));        // 8 MB

  cvt_x_kernel<<<dim3(4096), dim3(256), 0, stream>>>(x, xb);
  cvt_w_kernel<<<dim3(1024, 4), dim3(256), 0, stream>>>(Wq, Wk, Wv, Wo, wb);
  gemm_qkv_kernel<<<dim3(8, 32, 3), dim3(256), 0, stream>>>(xb, wb, bq, bk, bv, qkv);
  attn_kernel<<<dim3(32, 32), dim3(256), 0, stream>>>(
      qkv, qkv + (size_t)4096 * DM, qkv + (size_t)2 * 4096 * DM, ob);
  gemm_out_kernel<<<dim3(8, 32), dim3(256), 0, stream>>>(
      ob, wb + (size_t)3 * DM * DM, bo, (float*)d_out);
}

// Round 4
// 207.245 us; speedup vs baseline: 1.4386x; 1.4386x over previous
//
#include <hip/hip_runtime.h>

// ---------------------------------------------------------------------------
// StandardMultiHeadAttention: B=2, S=2048, D=1024, H=16, Dh=64, causal.
// fp32->f16 convert -> QKV GEMM (epilogue scatters into MFMA-FRAGMENT-MAJOR
// layouts) -> flash attention (coalesced frag loads, S^T tiles, static-base
// softmax, no barriers) -> output GEMM (fp32 out).
//
// Workspace (48 MB):
//   [0,8M)    xb : x f16 [4096,1024]
//   [8M,16M)  wb : Wq,Wk,Wv,Wo f16 (row=out, K-major)
//   [16M,24M) QF : Q frag-major (pre-scaled by 0.125*log2e)
//   [24M,32M) KF : K frag-major
//   [32M,40M) VF : V^T frag-major
//   [40M,48M) ob : attention output [B,S,1024] f16
//
// Frag layouts (per bh, f16 units, l = quad*16+ln):
//   QF/KF: idx = bh*131072 + (s>>4)*1024 + (d>>5)*512 + ((d>>3)&3)*128
//                 + (s&15)*8 + (d&7)         // A/B-frag: lane reads l*16B
//   VF:    idx = bh*131072 + (s>>5)*2048 + (d>>4)*512 + ((s>>3)&3)*128
//                 + (d&15)*8 + (s&7)         // V^T A-frag
//
// R3 post-mortem: strided 16B/lane gathers (16 lines/instr) + no prefetch =
// latency-bound (MfmaUtil 4.6%). R1 was barrier-convoy bound, not LDS-BW.
// R4: every attn load is base+lane*16 (1KB coalesced), reg double-buffer,
// zero barriers, softmax with m=0 (scores bounded ~8; fp32 safe to e^88).
// ---------------------------------------------------------------------------

typedef _Float16 f16x8 __attribute__((ext_vector_type(8)));
typedef _Float16 f16x4 __attribute__((ext_vector_type(4)));
typedef float f32x4 __attribute__((ext_vector_type(4)));

#define S_  2048
#define DM  1024
#define NH  16
#define DH  64

__device__ __forceinline__ void gload_lds16(const void* g, void* s) {
  __builtin_amdgcn_global_load_lds(
      (const __attribute__((address_space(1))) void*)g,
      (__attribute__((address_space(3))) void*)s, 16, 0, 0);
}

// ----------------------------- convert kernels -----------------------------

__global__ void cvt_x_kernel(const float* __restrict__ src,
                             _Float16* __restrict__ dst) {
  const int i = blockIdx.x * 256 + threadIdx.x;
  const float4 v = ((const float4*)src)[i];
  f16x4 h;
  h[0] = (_Float16)v.x; h[1] = (_Float16)v.y;
  h[2] = (_Float16)v.z; h[3] = (_Float16)v.w;
  ((f16x4*)dst)[i] = h;
}

__global__ void cvt_w_kernel(const float* __restrict__ w0,
                             const float* __restrict__ w1,
                             const float* __restrict__ w2,
                             const float* __restrict__ w3,
                             _Float16* __restrict__ dst) {
  const int y = blockIdx.y;
  const float* src = (y == 0) ? w0 : (y == 1) ? w1 : (y == 2) ? w2 : w3;
  const int i = blockIdx.x * 256 + threadIdx.x;
  const float4 v = ((const float4*)src)[i];
  f16x4 h;
  h[0] = (_Float16)v.x; h[1] = (_Float16)v.y;
  h[2] = (_Float16)v.z; h[3] = (_Float16)v.w;
  ((f16x4*)(dst + (size_t)y * (DM * DM)))[i] = h;
}

// ------------------------------- GEMM core ---------------------------------

__device__ __forceinline__ void gemm_core_k1024(
    const _Float16* __restrict__ A, const _Float16* __restrict__ W,
    _Float16* As, _Float16* Ws, f32x4 acc[4][4], int m0, int n0)
{
  const int t = threadIdx.x;
  const int w = t >> 6, l = t & 63;
  const int quad = l >> 4, ln = l & 15;
  const int wm = (w >> 1) << 6, wn = (w & 1) << 6;
  const int srow = l >> 2, scol = (l & 3) << 3;

  for (int k0 = 0; k0 < DM; k0 += 32) {
#pragma unroll
    for (int i = 0; i < 2; ++i) {
      const int ra = w * 32 + i * 16;
      gload_lds16(&A[(size_t)(m0 + ra + srow) * DM + k0 + scol], &As[ra * 32]);
      gload_lds16(&W[(size_t)(n0 + ra + srow) * DM + k0 + scol], &Ws[ra * 32]);
    }
    __syncthreads();

    f16x8 af[4], bf[4];
#pragma unroll
    for (int mi = 0; mi < 4; ++mi)
      af[mi] = *(const f16x8*)&As[(wm + mi * 16 + ln) * 32 + quad * 8];
#pragma unroll
    for (int ni = 0; ni < 4; ++ni)
      bf[ni] = *(const f16x8*)&Ws[(wn + ni * 16 + ln) * 32 + quad * 8];
#pragma unroll
    for (int mi = 0; mi < 4; ++mi)
#pragma unroll
      for (int ni = 0; ni < 4; ++ni)
        acc[mi][ni] = __builtin_amdgcn_mfma_f32_16x16x32_f16(
            af[mi], bf[ni], acc[mi][ni], 0, 0, 0);
    __syncthreads();
  }
}

// z=0: Q (bias, *0.125*log2e, QF layout); z=1: K (bias, KF layout);
// z=2: V (bias, VF layout)
__global__ __launch_bounds__(256, 2) void gemm_qkv_kernel(
    const _Float16* __restrict__ xb, const _Float16* __restrict__ wb,
    const float* __restrict__ bq, const float* __restrict__ bk,
    const float* __restrict__ bv, _Float16* __restrict__ qkv)
{
  __shared__ _Float16 As[128 * 32];
  __shared__ _Float16 Ws[128 * 32];
  const int z = blockIdx.z;
  const _Float16* W = wb + (size_t)z * (DM * DM);
  const float* bias = (z == 0) ? bq : ((z == 1) ? bk : bv);
  _Float16* out = qkv + (size_t)z * 4194304;

  const f32x4 z4 = {0.f, 0.f, 0.f, 0.f};
  f32x4 acc[4][4];
#pragma unroll
  for (int mi = 0; mi < 4; ++mi)
#pragma unroll
    for (int ni = 0; ni < 4; ++ni) acc[mi][ni] = z4;

  const int m0 = blockIdx.y * 128, n0 = blockIdx.x * 128;
  gemm_core_k1024(xb, W, As, Ws, acc, m0, n0);

  const int t = threadIdx.x, w = t >> 6, l = t & 63;
  const int quad = l >> 4, ln = l & 15;
  const int wm = (w >> 1) << 6, wn = (w & 1) << 6;
  // fold 1/sqrt(Dh) * log2(e) into Q so attention uses exp2
  const float scale = (z == 0) ? 0.18033688f : 1.0f;

#pragma unroll
  for (int ni = 0; ni < 4; ++ni) {
    const int c = n0 + wn + ni * 16 + ln;
    const float bias_c = bias[c];
    const int h = c >> 6, d = c & 63;
#pragma unroll
    for (int mi = 0; mi < 4; ++mi) {
      const int mb = m0 + wm + mi * 16 + quad * 4;
#pragma unroll
      for (int r = 0; r < 4; ++r) {
        const int mg = mb + r;
        const int b = mg >> 11, s = mg & 2047;
        const int bh = b * NH + h;
        const float v = (acc[mi][ni][r] + bias_c) * scale;
        size_t idx;
        if (z == 2)
          idx = (size_t)bh * 131072 + (s >> 5) * 2048 + (d >> 4) * 512 +
                ((s >> 3) & 3) * 128 + (d & 15) * 8 + (s & 7);
        else
          idx = (size_t)bh * 131072 + (s >> 4) * 1024 + (d >> 5) * 512 +
                ((d >> 3) & 3) * 128 + (s & 15) * 8 + (d & 7);
        out[idx] = (_Float16)v;
      }
    }
  }
}

__global__ __launch_bounds__(256, 2) void gemm_out_kernel(
    const _Float16* __restrict__ ob, const _Float16* __restrict__ wo,
    const float* __restrict__ bo, float* __restrict__ out)
{
  __shared__ _Float16 As[128 * 32];
  __shared__ _Float16 Ws[128 * 32];
  const f32x4 z4 = {0.f, 0.f, 0.f, 0.f};
  f32x4 acc[4][4];
#pragma unroll
  for (int mi = 0; mi < 4; ++mi)
#pragma unroll
    for (int ni = 0; ni < 4; ++ni) acc[mi][ni] = z4;

  const int m0 = blockIdx.y * 128, n0 = blockIdx.x * 128;
  gemm_core_k1024(ob, wo, As, Ws, acc, m0, n0);

  const int t = threadIdx.x, w = t >> 6, l = t & 63;
  const int quad = l >> 4, ln = l & 15;
  const int wm = (w >> 1) << 6, wn = (w & 1) << 6;

#pragma unroll
  for (int ni = 0; ni < 4; ++ni) {
    const int c = n0 + wn + ni * 16 + ln;
    const float bias_c = bo[c];
#pragma unroll
    for (int mi = 0; mi < 4; ++mi) {
      const int mb = m0 + wm + mi * 16 + quad * 4;
#pragma unroll
      for (int r = 0; r < 4; ++r)
        out[(size_t)(mb + r) * DM + c] = acc[mi][ni][r] + bias_c;
    }
  }
}

// ---------------------------- flash attention ------------------------------
// 1 wave/block (64 thr). Wave owns 32 q rows; kv-tiles of 32. All operand
// loads are base+lane*16 coalesced from frag-major tensors. S^T = K*Q^T,
// O^T = V^T*P^T (operand-swapped MFMA). Static-base softmax (m=0, exp2).
// P^T through wave-private LDS (stride 40 f16: b64 writes / b128 reads,
// conflict-free). Register double-buffered K/V prefetch, zero barriers.

struct KVfrag { f16x8 k[4]; f16x8 v[4]; };

__device__ __forceinline__ KVfrag load_tile(const _Float16* __restrict__ kb_,
                                            const _Float16* __restrict__ vb_,
                                            int t, int l) {
  KVfrag f;
#pragma unroll
  for (int i = 0; i < 4; ++i)
    f.k[i] = *(const f16x8*)(kb_ + (size_t)(t * 4 + i) * 512 + l * 8);
#pragma unroll
  for (int i = 0; i < 4; ++i)
    f.v[i] = *(const f16x8*)(vb_ + (size_t)(t * 4 + i) * 512 + l * 8);
  return f;
}

template <bool DIAG>
__device__ __forceinline__ void compute_tile(
    const KVfrag& kv, const f16x8 (&qf)[2][2], f32x4 (&oacc)[4][2],
    float (&l_i)[2], _Float16* Ps, int quad, int ln)
{
  const f32x4 z4 = {0.f, 0.f, 0.f, 0.f};
  f32x4 sacc[2][2];
#pragma unroll
  for (int mi = 0; mi < 2; ++mi)
#pragma unroll
    for (int qc = 0; qc < 2; ++qc) sacc[mi][qc] = z4;

  // S^T tile: A = K frag (m=kv), B = Q frag (n=q)
#pragma unroll
  for (int ks = 0; ks < 2; ++ks)
#pragma unroll
    for (int mi = 0; mi < 2; ++mi)
#pragma unroll
      for (int qc = 0; qc < 2; ++qc)
        sacc[mi][qc] = __builtin_amdgcn_mfma_f32_16x16x32_f16(
            kv.k[mi * 2 + ks], qf[qc][ks], sacc[mi][qc], 0, 0, 0);

  // static-base softmax: p = 2^s (Q pre-scaled by 0.125*log2e)
#pragma unroll
  for (int qc = 0; qc < 2; ++qc) {
    float rs = 0.f;
#pragma unroll
    for (int mi = 0; mi < 2; ++mi) {
      float p[4];
#pragma unroll
      for (int r = 0; r < 4; ++r) {
        p[r] = exp2f(sacc[mi][qc][r]);
        if (DIAG && (mi * 16 + quad * 4 + r > qc * 16 + ln)) p[r] = 0.f;
        rs += p[r];
      }
      f16x4 pk;
      pk[0] = (_Float16)p[0]; pk[1] = (_Float16)p[1];
      pk[2] = (_Float16)p[2]; pk[3] = (_Float16)p[3];
      *(f16x4*)&Ps[(qc * 16 + ln) * 40 + mi * 16 + quad * 4] = pk;
    }
    rs += __shfl_xor(rs, 16);
    rs += __shfl_xor(rs, 32);
    l_i[qc] += rs;
  }

  // P^T B-frags (row q=ln, k=kv contiguous) — wave-private, no barrier
  f16x8 pb[2];
#pragma unroll
  for (int qc = 0; qc < 2; ++qc)
    pb[qc] = *(const f16x8*)&Ps[(qc * 16 + ln) * 40 + quad * 8];

  // O^T += V^T * P^T
#pragma unroll
  for (int di = 0; di < 4; ++di)
#pragma unroll
    for (int qc = 0; qc < 2; ++qc)
      oacc[di][qc] = __builtin_amdgcn_mfma_f32_16x16x32_f16(
          kv.v[di], pb[qc], oacc[di][qc], 0, 0, 0);
}

__global__ __launch_bounds__(64) void attn_kernel(
    const _Float16* __restrict__ QF, const _Float16* __restrict__ KF,
    const _Float16* __restrict__ VF, _Float16* __restrict__ Ob)
{
  __shared__ _Float16 Ps[2 * 16 * 40];

  // XCD-swizzle: XCD = blockIdx%8 (heuristic): each XCD sees 4 heads (2MB L2
  // working set); within XCD, longest q-waves first (tail balance).
  const int i = blockIdx.x;
  const int jj = i >> 3;
  const int bh = (i & 7) + ((jj & 3) << 3);
  const int qw = 63 - (jj >> 2);
  const int q0 = qw << 5;

  const int l = threadIdx.x, quad = l >> 4, ln = l & 15;
  const _Float16* kb_ = KF + (size_t)bh * 131072;
  const _Float16* vb_ = VF + (size_t)bh * 131072;
  const _Float16* qb_ = QF + (size_t)bh * 131072;

  f16x8 qf[2][2];
#pragma unroll
  for (int qc = 0; qc < 2; ++qc)
#pragma unroll
    for (int ks = 0; ks < 2; ++ks)
      qf[qc][ks] = *(const f16x8*)
          (qb_ + (size_t)((2 * qw + qc) * 2 + ks) * 512 + l * 8);

  const f32x4 z4 = {0.f, 0.f, 0.f, 0.f};
  f32x4 oacc[4][2];
#pragma unroll
  for (int di = 0; di < 4; ++di)
#pragma unroll
    for (int qc = 0; qc < 2; ++qc) oacc[di][qc] = z4;
  float l_i[2] = {0.f, 0.f};

  const int ntf = q0 >> 5;   // full (unmasked) kv tiles; tile ntf = diagonal
  KVfrag b0 = load_tile(kb_, vb_, 0, l);
  KVfrag b1;
  for (int t = 0; t < ntf; ++t) {
    if ((t & 1) == 0) {
      b1 = load_tile(kb_, vb_, t + 1, l);
      compute_tile<false>(b0, qf, oacc, l_i, Ps, quad, ln);
    } else {
      b0 = load_tile(kb_, vb_, t + 1, l);
      compute_tile<false>(b1, qf, oacc, l_i, Ps, quad, ln);
    }
  }
  if (ntf & 1) compute_tile<true>(b1, qf, oacc, l_i, Ps, quad, ln);
  else         compute_tile<true>(b0, qf, oacc, l_i, Ps, quad, ln);

  // epilogue: O = O^T/l -> [B,S,H*64] f16 (lane holds col q=ln, rows d)
  const int bidx = bh >> 4, h = bh & 15;
#pragma unroll
  for (int qc = 0; qc < 2; ++qc) {
    const float inv = 1.0f / l_i[qc];
    const int q = q0 + qc * 16 + ln;
    _Float16* orow = Ob + (size_t)(bidx * S_ + q) * DM + h * DH + quad * 4;
#pragma unroll
    for (int di = 0; di < 4; ++di) {
      f16x4 o4;
#pragma unroll
      for (int r = 0; r < 4; ++r) o4[r] = (_Float16)(oacc[di][qc][r] * inv);
      *(f16x4*)(orow + di * 16) = o4;
    }
  }
}

// ------------------------------- launcher ----------------------------------

extern "C" void kernel_launch(void* const* d_in, const int* in_sizes, int n_in,
                              void* d_out, int out_size, void* d_ws, size_t ws_size,
                              hipStream_t stream) {
  (void)in_sizes; (void)n_in; (void)out_size; (void)ws_size;
  const float* x  = (const float*)d_in[0];
  const float* Wq = (const float*)d_in[1];
  const float* bq = (const float*)d_in[2];
  const float* Wk = (const float*)d_in[3];
  const float* bk = (const float*)d_in[4];
  const float* Wv = (const float*)d_in[5];
  const float* bv = (const float*)d_in[6];
  const float* Wo = (const float*)d_in[7];
  const float* bo = (const float*)d_in[8];

  char* ws = (char*)d_ws;
  _Float16* xb  = (_Float16*)(ws);                      // 8 MB
  _Float16* wb  = (_Float16*)(ws + (8u << 20));         // 4 x 2 MB
  _Float16* qkv = (_Float16*)(ws + (16u << 20));        // QF,KF,VF 8 MB each
  _Float16* ob  = (_Float16*)(ws + (40u << 20));        // 8 MB

  cvt_x_kernel<<<dim3(4096), dim3(256), 0, stream>>>(x, xb);
  cvt_w_kernel<<<dim3(1024, 4), dim3(256), 0, stream>>>(Wq, Wk, Wv, Wo, wb);
  gemm_qkv_kernel<<<dim3(8, 32, 3), dim3(256), 0, stream>>>(xb, wb, bq, bk, bv, qkv);
  attn_kernel<<<dim3(2048), dim3(64), 0, stream>>>(
      qkv, qkv + 4194304, qkv + 2 * 4194304, ob);
  gemm_out_kernel<<<dim3(8, 32), dim3(256), 0, stream>>>(
      ob, wb + (size_t)3 * DM * DM, bo, (float*)d_out);
}

// Round 6
// 185.009 us; speedup vs baseline: 1.6115x; 1.1202x over previous
//
#include <hip/hip_runtime.h>

// ---------------------------------------------------------------------------
// StandardMultiHeadAttention: B=2, S=2048, D=1024, H=16, Dh=64, causal.
// fp32->f16 convert -> QKV GEMM (epilogue scatters into MFMA-FRAGMENT-MAJOR
// layouts) -> flash attention (coalesced frag loads, S^T tiles, static-base
// softmax) -> output GEMM (fp32 out).
//
// Workspace (48 MB):
//   [0,8M)    xb : x f16 [4096,1024]
//   [8M,16M)  wb : Wq,Wk,Wv,Wo f16 (row=out, K-major)
//   [16M,24M) QF : Q frag-major (pre-scaled by 0.125*log2e)
//   [24M,32M) KF : K frag-major
//   [32M,40M) VF : V^T frag-major
//   [40M,48M) ob : attention output [B,S,1024] f16
//
// R4 post-mortem: attn at 12% occupancy (2048 1-wave blocks, triangle
// imbalance) -> 1 wave/SIMD -> serial VALU/MFMA stream (VALU 45%, MFMA 10%).
// R5: balanced pairs (qw=p & 63-p = 65 kv-tiles const) split by kv-PARITY
// across 2 waves/block (disjoint tiles -> L2 traffic unchanged), 1024 blocks
// = 8 waves/CU steady. Partial (O,l) merged via LDS (static-base softmax =>
// merge is a plain sum). VALU trims: raw v_exp_f32, packed cvt_pkrtz,
// XOR-swizzled Ps.
// R6: fix cvt_pkrtz return-type mismatch (bit_cast __fp16x2 -> f16x2).
// ---------------------------------------------------------------------------

typedef _Float16 f16x8 __attribute__((ext_vector_type(8)));
typedef _Float16 f16x4 __attribute__((ext_vector_type(4)));
typedef _Float16 f16x2 __attribute__((ext_vector_type(2)));
typedef float f32x4 __attribute__((ext_vector_type(4)));

#define S_  2048
#define DM  1024
#define NH  16
#define DH  64

__device__ __forceinline__ void gload_lds16(const void* g, void* s) {
  __builtin_amdgcn_global_load_lds(
      (const __attribute__((address_space(1))) void*)g,
      (__attribute__((address_space(3))) void*)s, 16, 0, 0);
}

__device__ __forceinline__ f16x2 pkrtz(float a, float b) {
  return __builtin_bit_cast(f16x2, __builtin_amdgcn_cvt_pkrtz(a, b));
}

// ----------------------------- convert kernels -----------------------------

__global__ void cvt_x_kernel(const float* __restrict__ src,
                             _Float16* __restrict__ dst) {
  const int i = blockIdx.x * 256 + threadIdx.x;
  const float4 v = ((const float4*)src)[i];
  f16x4 h;
  h[0] = (_Float16)v.x; h[1] = (_Float16)v.y;
  h[2] = (_Float16)v.z; h[3] = (_Float16)v.w;
  ((f16x4*)dst)[i] = h;
}

__global__ void cvt_w_kernel(const float* __restrict__ w0,
                             const float* __restrict__ w1,
                             const float* __restrict__ w2,
                             const float* __restrict__ w3,
                             _Float16* __restrict__ dst) {
  const int y = blockIdx.y;
  const float* src = (y == 0) ? w0 : (y == 1) ? w1 : (y == 2) ? w2 : w3;
  const int i = blockIdx.x * 256 + threadIdx.x;
  const float4 v = ((const float4*)src)[i];
  f16x4 h;
  h[0] = (_Float16)v.x; h[1] = (_Float16)v.y;
  h[2] = (_Float16)v.z; h[3] = (_Float16)v.w;
  ((f16x4*)(dst + (size_t)y * (DM * DM)))[i] = h;
}

// ------------------------------- GEMM core ---------------------------------

__device__ __forceinline__ void gemm_core_k1024(
    const _Float16* __restrict__ A, const _Float16* __restrict__ W,
    _Float16* As, _Float16* Ws, f32x4 acc[4][4], int m0, int n0)
{
  const int t = threadIdx.x;
  const int w = t >> 6, l = t & 63;
  const int quad = l >> 4, ln = l & 15;
  const int wm = (w >> 1) << 6, wn = (w & 1) << 6;
  const int srow = l >> 2, scol = (l & 3) << 3;

  for (int k0 = 0; k0 < DM; k0 += 32) {
#pragma unroll
    for (int i = 0; i < 2; ++i) {
      const int ra = w * 32 + i * 16;
      gload_lds16(&A[(size_t)(m0 + ra + srow) * DM + k0 + scol], &As[ra * 32]);
      gload_lds16(&W[(size_t)(n0 + ra + srow) * DM + k0 + scol], &Ws[ra * 32]);
    }
    __syncthreads();

    f16x8 af[4], bf[4];
#pragma unroll
    for (int mi = 0; mi < 4; ++mi)
      af[mi] = *(const f16x8*)&As[(wm + mi * 16 + ln) * 32 + quad * 8];
#pragma unroll
    for (int ni = 0; ni < 4; ++ni)
      bf[ni] = *(const f16x8*)&Ws[(wn + ni * 16 + ln) * 32 + quad * 8];
#pragma unroll
    for (int mi = 0; mi < 4; ++mi)
#pragma unroll
      for (int ni = 0; ni < 4; ++ni)
        acc[mi][ni] = __builtin_amdgcn_mfma_f32_16x16x32_f16(
            af[mi], bf[ni], acc[mi][ni], 0, 0, 0);
    __syncthreads();
  }
}

// z=0: Q (bias, *0.125*log2e, QF layout); z=1: K (bias, KF layout);
// z=2: V (bias, VF layout)
__global__ __launch_bounds__(256, 2) void gemm_qkv_kernel(
    const _Float16* __restrict__ xb, const _Float16* __restrict__ wb,
    const float* __restrict__ bq, const float* __restrict__ bk,
    const float* __restrict__ bv, _Float16* __restrict__ qkv)
{
  __shared__ _Float16 As[128 * 32];
  __shared__ _Float16 Ws[128 * 32];
  const int z = blockIdx.z;
  const _Float16* W = wb + (size_t)z * (DM * DM);
  const float* bias = (z == 0) ? bq : ((z == 1) ? bk : bv);
  _Float16* out = qkv + (size_t)z * 4194304;

  const f32x4 z4 = {0.f, 0.f, 0.f, 0.f};
  f32x4 acc[4][4];
#pragma unroll
  for (int mi = 0; mi < 4; ++mi)
#pragma unroll
    for (int ni = 0; ni < 4; ++ni) acc[mi][ni] = z4;

  const int m0 = blockIdx.y * 128, n0 = blockIdx.x * 128;
  gemm_core_k1024(xb, W, As, Ws, acc, m0, n0);

  const int t = threadIdx.x, w = t >> 6, l = t & 63;
  const int quad = l >> 4, ln = l & 15;
  const int wm = (w >> 1) << 6, wn = (w & 1) << 6;
  // fold 1/sqrt(Dh) * log2(e) into Q so attention uses exp2
  const float scale = (z == 0) ? 0.18033688f : 1.0f;

#pragma unroll
  for (int ni = 0; ni < 4; ++ni) {
    const int c = n0 + wn + ni * 16 + ln;
    const float bias_c = bias[c];
    const int h = c >> 6, d = c & 63;
#pragma unroll
    for (int mi = 0; mi < 4; ++mi) {
      const int mb = m0 + wm + mi * 16 + quad * 4;
#pragma unroll
      for (int r = 0; r < 4; ++r) {
        const int mg = mb + r;
        const int b = mg >> 11, s = mg & 2047;
        const int bh = b * NH + h;
        const float v = (acc[mi][ni][r] + bias_c) * scale;
        size_t idx;
        if (z == 2)
          idx = (size_t)bh * 131072 + (s >> 5) * 2048 + (d >> 4) * 512 +
                ((s >> 3) & 3) * 128 + (d & 15) * 8 + (s & 7);
        else
          idx = (size_t)bh * 131072 + (s >> 4) * 1024 + (d >> 5) * 512 +
                ((d >> 3) & 3) * 128 + (s & 15) * 8 + (d & 7);
        out[idx] = (_Float16)v;
      }
    }
  }
}

__global__ __launch_bounds__(256, 2) void gemm_out_kernel(
    const _Float16* __restrict__ ob, const _Float16* __restrict__ wo,
    const float* __restrict__ bo, float* __restrict__ out)
{
  __shared__ _Float16 As[128 * 32];
  __shared__ _Float16 Ws[128 * 32];
  const f32x4 z4 = {0.f, 0.f, 0.f, 0.f};
  f32x4 acc[4][4];
#pragma unroll
  for (int mi = 0; mi < 4; ++mi)
#pragma unroll
    for (int ni = 0; ni < 4; ++ni) acc[mi][ni] = z4;

  const int m0 = blockIdx.y * 128, n0 = blockIdx.x * 128;
  gemm_core_k1024(ob, wo, As, Ws, acc, m0, n0);

  const int t = threadIdx.x, w = t >> 6, l = t & 63;
  const int quad = l >> 4, ln = l & 15;
  const int wm = (w >> 1) << 6, wn = (w & 1) << 6;

#pragma unroll
  for (int ni = 0; ni < 4; ++ni) {
    const int c = n0 + wn + ni * 16 + ln;
    const float bias_c = bo[c];
#pragma unroll
    for (int mi = 0; mi < 4; ++mi) {
      const int mb = m0 + wm + mi * 16 + quad * 4;
#pragma unroll
      for (int r = 0; r < 4; ++r)
        out[(size_t)(mb + r) * DM + c] = acc[mi][ni][r] + bias_c;
    }
  }
}

// ---------------------------- flash attention ------------------------------
// 1024 blocks x 2 waves. Block = (head bh, pair p): waves par=0/1 take kv
// tiles of parity par for q-tiles {63-p, p} (65 tiles/pair, ~33/wave, all
// waves equal). Partial O,l merged via LDS (static-base softmax => plain sum).
// All operand loads base+lane*16 coalesced from frag-major tensors.

struct KVfrag { f16x8 k[4]; f16x8 v[4]; };

__device__ __forceinline__ KVfrag load_tile(const _Float16* __restrict__ kb_,
                                            const _Float16* __restrict__ vb_,
                                            int t, int l) {
  KVfrag f;
#pragma unroll
  for (int i = 0; i < 4; ++i)
    f.k[i] = *(const f16x8*)(kb_ + (size_t)(t * 4 + i) * 512 + l * 8);
#pragma unroll
  for (int i = 0; i < 4; ++i)
    f.v[i] = *(const f16x8*)(vb_ + (size_t)(t * 4 + i) * 512 + l * 8);
  return f;
}

template <bool DIAG>
__device__ __forceinline__ void compute_tile(
    const KVfrag& kv, const f16x8 (&qf)[2][2], f32x4 (&oacc)[4][2],
    float (&l_i)[2], _Float16* Ps, int quad, int ln)
{
  const f32x4 z4 = {0.f, 0.f, 0.f, 0.f};
  f32x4 sacc[2][2];
#pragma unroll
  for (int mi = 0; mi < 2; ++mi)
#pragma unroll
    for (int qc = 0; qc < 2; ++qc) sacc[mi][qc] = z4;

  // S^T tile: A = K frag (m=kv), B = Q frag (n=q)
#pragma unroll
  for (int ks = 0; ks < 2; ++ks)
#pragma unroll
    for (int mi = 0; mi < 2; ++mi)
#pragma unroll
      for (int qc = 0; qc < 2; ++qc)
        sacc[mi][qc] = __builtin_amdgcn_mfma_f32_16x16x32_f16(
            kv.k[mi * 2 + ks], qf[qc][ks], sacc[mi][qc], 0, 0, 0);

  // static-base softmax: p = 2^s (Q pre-scaled by 0.125*log2e)
  const int sw = (ln & 3) << 1;   // even XOR key: keeps 16B read alignment
#pragma unroll
  for (int qc = 0; qc < 2; ++qc) {
    float rs = 0.f;
#pragma unroll
    for (int mi = 0; mi < 2; ++mi) {
      float p[4];
#pragma unroll
      for (int r = 0; r < 4; ++r) {
        p[r] = __builtin_amdgcn_exp2f(sacc[mi][qc][r]);
        if (DIAG && (mi * 16 + quad * 4 + r > qc * 16 + ln)) p[r] = 0.f;
        rs += p[r];
      }
      const f16x2 lo = pkrtz(p[0], p[1]);
      const f16x2 hi = pkrtz(p[2], p[3]);
      const f16x4 pk = __builtin_shufflevector(lo, hi, 0, 1, 2, 3);
      const int g = (mi * 4 + quad) ^ sw;          // 8B granule, swizzled
      *(f16x4*)&Ps[(qc * 16 + ln) * 40 + g * 4] = pk;
    }
    rs += __shfl_xor(rs, 16);
    rs += __shfl_xor(rs, 32);
    l_i[qc] += rs;
  }

  // P^T B-frags (row q=ln, kv contiguous) — wave-private, no barrier
  f16x8 pb[2];
#pragma unroll
  for (int qc = 0; qc < 2; ++qc) {
    const int g2 = (quad * 2) ^ sw;                // even -> pair contiguous
    pb[qc] = *(const f16x8*)&Ps[(qc * 16 + ln) * 40 + g2 * 4];
  }

  // O^T += V^T * P^T
#pragma unroll
  for (int di = 0; di < 4; ++di)
#pragma unroll
    for (int qc = 0; qc < 2; ++qc)
      oacc[di][qc] = __builtin_amdgcn_mfma_f32_16x16x32_f16(
          kv.v[di], pb[qc], oacc[di][qc], 0, 0, 0);
}

__global__ __launch_bounds__(128, 2) void attn_kernel(
    const _Float16* __restrict__ QF, const _Float16* __restrict__ KF,
    const _Float16* __restrict__ VF, _Float16* __restrict__ Ob)
{
  __shared__ _Float16 Ps[2 * 32 * 40];   // per-wave P transpose buffers
  __shared__ float mrg[64 * 34];         // cross-wave (O,l) merge

  // block -> (bh, pair): XCD x = i&7 sees 4 heads (2MB KV <= 4MB L2/XCD)
  const int i = blockIdx.x;
  const int bh = ((i & 7) << 2) | ((i >> 3) & 3);
  const int p = i >> 5;                  // pair index 0..31

  const int tid = threadIdx.x;
  const int w = tid >> 6, l = tid & 63;  // w = kv parity (par)
  const int quad = l >> 4, ln = l & 15;

  const _Float16* qb_ = QF + (size_t)bh * 131072;
  const _Float16* kb_ = KF + (size_t)bh * 131072;
  const _Float16* vb_ = VF + (size_t)bh * 131072;
  _Float16* psw = Ps + w * (32 * 40);
  const int bidx = bh >> 4, h = bh & 15;

  const f32x4 z4 = {0.f, 0.f, 0.f, 0.f};

#pragma unroll
  for (int mem = 0; mem < 2; ++mem) {
    const int qw = (mem == 0) ? (63 - p) : p;   // long member first
    const int q0 = qw << 5;

    f16x8 qf[2][2];
#pragma unroll
    for (int qc = 0; qc < 2; ++qc)
#pragma unroll
      for (int ks = 0; ks < 2; ++ks)
        qf[qc][ks] = *(const f16x8*)
            (qb_ + (size_t)((2 * qw + qc) * 2 + ks) * 512 + l * 8);

    f32x4 oacc[4][2];
#pragma unroll
    for (int di = 0; di < 4; ++di)
#pragma unroll
      for (int qc = 0; qc < 2; ++qc) oacc[di][qc] = z4;
    float l_i[2] = {0.f, 0.f};

    // kv tiles t = w, w+2, ..., <= qw ; diag tile (t==qw) owned by parity qw&1
    const int n = (qw >= w) ? (((qw - w) >> 1) + 1) : 0;
    if (n > 0) {
      KVfrag b0 = load_tile(kb_, vb_, w, l);
      KVfrag b1;
      for (int k = 0; k + 1 < n; ++k) {
        const int tnext = w + 2 * (k + 1);
        if ((k & 1) == 0) {
          b1 = load_tile(kb_, vb_, tnext, l);
          compute_tile<false>(b0, qf, oacc, l_i, psw, quad, ln);
        } else {
          b0 = load_tile(kb_, vb_, tnext, l);
          compute_tile<false>(b1, qf, oacc, l_i, psw, quad, ln);
        }
      }
      const KVfrag& last = ((n - 1) & 1) ? b1 : b0;
      if (((qw - w) & 1) == 0)
        compute_tile<true>(last, qf, oacc, l_i, psw, quad, ln);
      else
        compute_tile<false>(last, qf, oacc, l_i, psw, quad, ln);
    }

    // merge partials: wave1 -> LDS, barrier, wave0 adds + writes O
    if (w == 1) {
#pragma unroll
      for (int di = 0; di < 4; ++di)
#pragma unroll
        for (int qc = 0; qc < 2; ++qc)
#pragma unroll
          for (int r = 0; r < 4; ++r)
            mrg[l * 34 + di * 8 + qc * 4 + r] = oacc[di][qc][r];
#pragma unroll
      for (int qc = 0; qc < 2; ++qc) mrg[l * 34 + 32 + qc] = l_i[qc];
    }
    __syncthreads();
    if (w == 0) {
#pragma unroll
      for (int qc = 0; qc < 2; ++qc) {
        const float inv = 1.0f / (l_i[qc] + mrg[l * 34 + 32 + qc]);
        const int q = q0 + qc * 16 + ln;
        _Float16* orow = Ob + (size_t)(bidx * S_ + q) * DM + h * DH + quad * 4;
#pragma unroll
        for (int di = 0; di < 4; ++di) {
          f16x4 o4;
#pragma unroll
          for (int r = 0; r < 4; ++r)
            o4[r] = (_Float16)((oacc[di][qc][r] +
                                mrg[l * 34 + di * 8 + qc * 4 + r]) * inv);
          *(f16x4*)(orow + di * 16) = o4;
        }
      }
    }
    __syncthreads();   // mrg reused by member 2
  }
}

// ------------------------------- launcher ----------------------------------

extern "C" void kernel_launch(void* const* d_in, const int* in_sizes, int n_in,
                              void* d_out, int out_size, void* d_ws, size_t ws_size,
                              hipStream_t stream) {
  (void)in_sizes; (void)n_in; (void)out_size; (void)ws_size;
  const float* x  = (const float*)d_in[0];
  const float* Wq = (const float*)d_in[1];
  const float* bq = (const float*)d_in[2];
  const float* Wk = (const float*)d_in[3];
  const float* bk = (const float*)d_in[4];
  const float* Wv = (const float*)d_in[5];
  const float* bv = (const float*)d_in[6];
  const float* Wo = (const float*)d_in[7];
  const float* bo = (const float*)d_in[8];

  char* ws = (char*)d_ws;
  _Float16* xb  = (_Float16*)(ws);                      // 8 MB
  _Float16* wb  = (_Float16*)(ws + (8u << 20));         // 4 x 2 MB
  _Float16* qkv = (_Float16*)(ws + (16u << 20));        // QF,KF,VF 8 MB each
  _Float16* ob  = (_Float16*)(ws + (40u << 20));        // 8 MB

  cvt_x_kernel<<<dim3(4096), dim3(256), 0, stream>>>(x, xb);
  cvt_w_kernel<<<dim3(1024, 4), dim3(256), 0, stream>>>(Wq, Wk, Wv, Wo, wb);
  gemm_qkv_kernel<<<dim3(8, 32, 3), dim3(256), 0, stream>>>(xb, wb, bq, bk, bv, qkv);
  attn_kernel<<<dim3(1024), dim3(128), 0, stream>>>(
      qkv, qkv + 4194304, qkv + 2 * 4194304, ob);
  gemm_out_kernel<<<dim3(8, 32), dim3(256), 0, stream>>>(
      ob, wb + (size_t)3 * DM * DM, bo, (float*)d_out);
}